// Round 1
// baseline (9666.682 us; speedup 1.0000x reference)
//
#include <hip/hip_runtime.h>
#include <hip/hip_bf16.h>
#include <math.h>

// Problem constants (MiniTrajectoryPredictor)
#define BB 32
#define TT 24
#define OO 128
#define HH 512
#define CTXD 256
#define HOR 48
#define NN (BB*OO)        // 4096
#define G3 (3*HH)         // 1536

// ---------------- GEMM: C = A(MxK) * W(NxK)^T + bias, optional exact GELU ----------------
// BM=128, BN=64, BK=16, 256 threads, 8x4 per thread. fp32 (no fp32 MFMA on CDNA4).
#define GBM 128
#define GBN 64
#define GBK 16

template<bool GELU>
__global__ __launch_bounds__(256) void gemm_nt(const float* __restrict__ A,
                                               const float* __restrict__ W,
                                               const float* __restrict__ bias,
                                               float* __restrict__ C,
                                               int M, int N, int K) {
    __shared__ float As[GBK][GBM + 4];
    __shared__ float Bs[GBK][GBN + 4];

    const int nbn = N / GBN;
    const int bx = blockIdx.x % nbn;
    const int by = blockIdx.x / nbn;
    const int m0 = by * GBM;
    const int n0 = bx * GBN;
    const int tid = threadIdx.x;
    const int ty = tid >> 4;          // 0..15
    const int tx = tid & 15;          // 0..15
    const int tm0 = ty * 8;
    const int tn0 = tx * 4;

    const int arow0 = tid >> 2;       // 0..63
    const int akq = (tid & 3) * 4;    // k sub-offset

    float acc[8][4];
#pragma unroll
    for (int i = 0; i < 8; i++)
#pragma unroll
        for (int j = 0; j < 4; j++) acc[i][j] = 0.f;

    for (int k0 = 0; k0 < K; k0 += GBK) {
        // A tile: 128x16 = 512 float4, 2 per thread (transpose into LDS)
#pragma unroll
        for (int L = 0; L < 2; L++) {
            int row = arow0 + L * 64;
            float4 v = *(const float4*)&A[(size_t)(m0 + row) * K + k0 + akq];
            As[akq + 0][row] = v.x; As[akq + 1][row] = v.y;
            As[akq + 2][row] = v.z; As[akq + 3][row] = v.w;
        }
        // B tile: 64x16 = 256 float4, 1 per thread
        {
            int row = tid >> 2;  // 0..63
            float4 v = *(const float4*)&W[(size_t)(n0 + row) * K + k0 + akq];
            Bs[akq + 0][row] = v.x; Bs[akq + 1][row] = v.y;
            Bs[akq + 2][row] = v.z; Bs[akq + 3][row] = v.w;
        }
        __syncthreads();
#pragma unroll
        for (int k = 0; k < GBK; k++) {
            float4 a0 = *(const float4*)&As[k][tm0];
            float4 a1 = *(const float4*)&As[k][tm0 + 4];
            float4 b  = *(const float4*)&Bs[k][tn0];
            float av[8] = {a0.x, a0.y, a0.z, a0.w, a1.x, a1.y, a1.z, a1.w};
            float bv[4] = {b.x, b.y, b.z, b.w};
#pragma unroll
            for (int i = 0; i < 8; i++)
#pragma unroll
                for (int j = 0; j < 4; j++)
                    acc[i][j] = fmaf(av[i], bv[j], acc[i][j]);
        }
        __syncthreads();
    }

    float4 bv4 = *(const float4*)&bias[n0 + tn0];
    float bb[4] = {bv4.x, bv4.y, bv4.z, bv4.w};
#pragma unroll
    for (int i = 0; i < 8; i++) {
        float4 o;
        float* op = &o.x;
#pragma unroll
        for (int j = 0; j < 4; j++) {
            float v = acc[i][j] + bb[j];
            if (GELU) v = 0.5f * v * (1.0f + erff(v * 0.70710678118654752440f));
            op[j] = v;
        }
        *(float4*)&C[(size_t)(m0 + tm0 + i) * N + n0 + tn0] = o;
    }
}

// ---------------- init: h = 0, state = seq[:, -1] ----------------
__global__ __launch_bounds__(256) void init_kernel(const float* __restrict__ traj,
                                                   float* __restrict__ h,
                                                   float* __restrict__ state) {
    int idx = blockIdx.x * 256 + threadIdx.x;   // 0 .. NN*HH-1
    h[idx] = 0.f;
    if (idx < NN * 2) {
        int n = idx >> 1, c = idx & 1;
        // traj[b, 23, o, c], b = n>>7, o = n&127
        state[idx] = traj[(size_t)(n >> 7) * (TT * OO * 2) + 23 * OO * 2 + (n & 127) * 2 + c];
    }
}

// ---------------- fused input weights: U = Wi*W_emb (1536x2), c = Wi*b_emb + bi ----------------
__global__ void fuse_kernel(const float* __restrict__ Wi_enc, const float* __restrict__ bi_enc,
                            const float* __restrict__ Wi_cell, const float* __restrict__ bi_cell,
                            const float* __restrict__ W_emb, const float* __restrict__ b_emb,
                            float* __restrict__ Ue, float* __restrict__ ce,
                            float* __restrict__ Ud, float* __restrict__ cd) {
    int idx = blockIdx.x * 256 + threadIdx.x;
    if (idx >= 2 * G3) return;
    int which = idx / G3, j = idx % G3;
    const float* Wi = which ? Wi_cell : Wi_enc;
    const float* bi = which ? bi_cell : bi_enc;
    float u0 = 0.f, u1 = 0.f, cc = bi[j];
    for (int k = 0; k < HH; k++) {
        float w = Wi[(size_t)j * HH + k];
        u0 = fmaf(w, W_emb[k * 2 + 0], u0);
        u1 = fmaf(w, W_emb[k * 2 + 1], u1);
        cc = fmaf(w, b_emb[k], cc);
    }
    float* U = which ? Ud : Ue;
    float* cv = which ? cd : ce;
    U[j * 2 + 0] = u0; U[j * 2 + 1] = u1; cv[j] = cc;
}

// ---------------- ctx = z_ctx @ W_ctx^T + b_ctx  (32x512) ----------------
__global__ void ctx_kernel(const float* __restrict__ z, const float* __restrict__ Wc,
                           const float* __restrict__ bc, float* __restrict__ ctx) {
    int idx = blockIdx.x * 256 + threadIdx.x;   // 0 .. 32*512-1
    int b = idx >> 9, j = idx & 511;
    float acc = bc[j];
    const float4* zp = (const float4*)(z + (size_t)b * CTXD);
    const float4* wp = (const float4*)(Wc + (size_t)j * CTXD);
    for (int k = 0; k < CTXD / 4; k++) {
        float4 a = zp[k], w = wp[k];
        acc = fmaf(a.x, w.x, fmaf(a.y, w.y, fmaf(a.z, w.z, fmaf(a.w, w.w, acc))));
    }
    ctx[idx] = acc;
}

// ---------------- GRU elementwise: gi via rank-2 fused weights; updates h in place ----------------
__global__ __launch_bounds__(256) void gru_kernel(const float* __restrict__ gh,
                                                  const float* __restrict__ U,
                                                  const float* __restrict__ cvec,
                                                  const float* __restrict__ xsrc, int enc_t,
                                                  const float* __restrict__ ctx, int add_ctx,
                                                  float* __restrict__ h) {
    int idx = blockIdx.x * 256 + threadIdx.x;    // 0 .. NN*HH-1
    int n = idx >> 9, j = idx & 511;
    float x0, x1;
    if (enc_t >= 0) {
        const float* p = xsrc + (size_t)(n >> 7) * (TT * OO * 2) + enc_t * OO * 2 + (n & 127) * 2;
        x0 = p[0]; x1 = p[1];
    } else {
        x0 = xsrc[n * 2]; x1 = xsrc[n * 2 + 1];
    }
    float gir = fmaf(x1, U[j * 2 + 1],            fmaf(x0, U[j * 2],            cvec[j]));
    float giz = fmaf(x1, U[(HH + j) * 2 + 1],     fmaf(x0, U[(HH + j) * 2],     cvec[HH + j]));
    float gin = fmaf(x1, U[(2 * HH + j) * 2 + 1], fmaf(x0, U[(2 * HH + j) * 2], cvec[2 * HH + j]));
    const float* ghp = gh + (size_t)n * G3;
    float r  = 1.f / (1.f + expf(-(gir + ghp[j])));
    float zz = 1.f / (1.f + expf(-(giz + ghp[HH + j])));
    float nn = tanhf(gin + r * ghp[2 * HH + j]);
    float hv = h[idx];
    float hn = (1.f - zz) * nn + zz * hv;
    if (add_ctx) hn += ctx[(size_t)(n >> 7) * HH + j];
    h[idx] = hn;
}

// ---------------- finalize: d = t1 @ W2^T + b2 ; bounded step ; state update ; write out ----------------
__global__ __launch_bounds__(256) void finalize_kernel(const float* __restrict__ t1,
                                                       const float* __restrict__ W2,
                                                       const float* __restrict__ b2,
                                                       float* __restrict__ state,
                                                       float* __restrict__ out, int t) {
    int wave = threadIdx.x >> 6, lane = threadIdx.x & 63;
    int n = blockIdx.x * 4 + wave;               // one wave per row
    const float* row = t1 + (size_t)n * HH;
    float a0 = 0.f, a1 = 0.f;
#pragma unroll
    for (int u = 0; u < 8; u++) {
        float v = row[u * 64 + lane];
        a0 = fmaf(v, W2[u * 64 + lane], a0);
        a1 = fmaf(v, W2[HH + u * 64 + lane], a1);
    }
#pragma unroll
    for (int off = 32; off > 0; off >>= 1) {
        a0 += __shfl_down(a0, off, 64);
        a1 += __shfl_down(a1, off, 64);
    }
    if (lane == 0) {
        float d0 = a0 + b2[0], d1 = a1 + b2[1];
        d0 = 2.0f * tanhf(d0 * 0.5f);
        d1 = 2.0f * tanhf(d1 * 0.5f);
        float s0 = state[n * 2] + d0;
        s0 = fminf(fmaxf(s0, -90.f), 90.f);
        float s1 = state[n * 2 + 1] + d1;
        float rr = fmodf(s1, 360.f);
        if (rr < 0.f) rr += 360.f;   // numpy/jnp.mod semantics
        state[n * 2] = s0; state[n * 2 + 1] = rr;
        float* op = out + (size_t)((n >> 7) * HOR + t) * (OO * 2) + (n & 127) * 2;
        op[0] = s0; op[1] = rr;
    }
}

extern "C" void kernel_launch(void* const* d_in, const int* in_sizes, int n_in,
                              void* d_out, int out_size, void* d_ws, size_t ws_size,
                              hipStream_t stream) {
    const float* z_ctx   = (const float*)d_in[0];
    const float* traj    = (const float*)d_in[1];
    const float* W_emb   = (const float*)d_in[2];
    const float* b_emb   = (const float*)d_in[3];
    const float* W_ctx   = (const float*)d_in[4];
    const float* b_ctx   = (const float*)d_in[5];
    const float* Wi_enc  = (const float*)d_in[6];
    const float* Wh_enc  = (const float*)d_in[7];
    const float* bi_enc  = (const float*)d_in[8];
    const float* bh_enc  = (const float*)d_in[9];
    const float* Wi_cell = (const float*)d_in[10];
    const float* Wh_cell = (const float*)d_in[11];
    const float* bi_cell = (const float*)d_in[12];
    const float* bh_cell = (const float*)d_in[13];
    const float* W1      = (const float*)d_in[14];
    const float* b1      = (const float*)d_in[15];
    const float* W2      = (const float*)d_in[16];
    const float* b2      = (const float*)d_in[17];
    float* out = (float*)d_out;

    // workspace layout (floats)
    float* ws = (float*)d_ws;
    float* h     = ws;                         // 4096*512
    float* gh    = h + (size_t)NN * HH;        // 4096*1536
    float* t1    = gh + (size_t)NN * G3;       // 4096*512
    float* state = t1 + (size_t)NN * HH;       // 4096*2
    float* ctxb  = state + NN * 2;             // 32*512
    float* Ue    = ctxb + BB * HH;             // 1536*2
    float* ce    = Ue + G3 * 2;                // 1536
    float* Ud    = ce + G3;                    // 1536*2
    float* cd    = Ud + G3 * 2;                // 1536

    const int ew_blocks = (NN * HH) / 256;     // 8192
    const int gemm_gh_blocks = (NN / GBM) * (G3 / GBN);  // 32*24 = 768
    const int gemm_w1_blocks = (NN / GBM) * (HH / GBN);  // 32*8  = 256

    init_kernel<<<ew_blocks, 256, 0, stream>>>(traj, h, state);
    fuse_kernel<<<(2 * G3 + 255) / 256, 256, 0, stream>>>(Wi_enc, bi_enc, Wi_cell, bi_cell,
                                                          W_emb, b_emb, Ue, ce, Ud, cd);
    ctx_kernel<<<(BB * HH) / 256, 256, 0, stream>>>(z_ctx, W_ctx, b_ctx, ctxb);

    // ---- encoder: 24 GRU steps ----
    for (int t = 0; t < TT; t++) {
        gemm_nt<false><<<gemm_gh_blocks, 256, 0, stream>>>(h, Wh_enc, bh_enc, gh, NN, G3, HH);
        gru_kernel<<<ew_blocks, 256, 0, stream>>>(gh, Ue, ce, traj, t, ctxb, (t == TT - 1) ? 1 : 0, h);
    }

    // ---- decoder: 48 steps ----
    for (int t = 0; t < HOR; t++) {
        gemm_nt<false><<<gemm_gh_blocks, 256, 0, stream>>>(h, Wh_cell, bh_cell, gh, NN, G3, HH);
        gru_kernel<<<ew_blocks, 256, 0, stream>>>(gh, Ud, cd, state, -1, nullptr, 0, h);
        gemm_nt<true><<<gemm_w1_blocks, 256, 0, stream>>>(h, W1, b1, t1, NN, HH, HH);
        finalize_kernel<<<NN / 4, 256, 0, stream>>>(t1, W2, b2, state, out, t);
    }
}

// Round 2
// 5791.245 us; speedup vs baseline: 1.6692x; 1.6692x over previous
//
#include <hip/hip_runtime.h>
#include <hip/hip_bf16.h>
#include <math.h>

// Problem constants (MiniTrajectoryPredictor)
#define BB 32
#define TT 24
#define OO 128
#define HH 512
#define CTXD 256
#define HOR 48
#define NN (BB*OO)        // 4096
#define G3 (3*HH)         // 1536
#define KE 544            // K extended: 512 h + x0,x1,1 + pad  -> 17 k-steps of 32
#define KS 17             // k-steps

typedef unsigned short ushortt;
typedef __attribute__((ext_vector_type(8))) short bf16x8;
typedef __attribute__((ext_vector_type(4))) float f32x4;

// ---- bf16 split helpers (hi = RN(x), lo = RN(x - hi); hi+lo carries ~17 bits) ----
__device__ __forceinline__ ushortt f2bf(float x) {
    union { float f; unsigned u; } v; v.f = x;
    unsigned r = v.u + 0x7FFF + ((v.u >> 16) & 1);
    return (ushortt)(r >> 16);
}
__device__ __forceinline__ float bf2f(ushortt b) {
    union { unsigned u; float f; } v; v.u = ((unsigned)b) << 16;
    return v.f;
}
__device__ __forceinline__ void splitbf(float x, ushortt& hi, ushortt& lo) {
    hi = f2bf(x);
    lo = f2bf(x - bf2f(hi));
}

// Fragment addressing (A-operand / B-operand layout for mfma_f32_16x16x32_bf16):
// element (row r, k) of a 16-row tile: lane = (k%32/8)*16 + (r%16), j = k%8,
// frag buffer [tile][ks][lane][j] (ushort). Stride per tile = KS*64*8 u16.

// ================= GEMM: C = A_ext(M x KE) * W_ext(N x KE)^T, split-bf16 3-MFMA =================
// BM = 128 (8 m-tiles), BN = 32*WNT, 256 threads (4 waves). Wave w: mt-half (w&1), nt-group (w>>1).
template<int WNT, bool GELU>
__global__ __launch_bounds__(256) void gemm_frag(const ushortt* __restrict__ Ah,
                                                 const ushortt* __restrict__ Al,
                                                 const ushortt* __restrict__ Bh,
                                                 const ushortt* __restrict__ Bl,
                                                 float* __restrict__ C, int N) {
    const int BN = 2 * WNT * 16;
    const int nbn = N / BN;
    const int bx = blockIdx.x % nbn;
    const int by = blockIdx.x / nbn;
    const int w = threadIdx.x >> 6;
    const int lane = threadIdx.x & 63;
    const int mtb = by * 8 + (w & 1) * 4;          // global m-tile base (4 tiles)
    const int ntb = bx * (2 * WNT) + (w >> 1) * WNT; // global n-tile base (WNT tiles)

    f32x4 acc[4][WNT];
#pragma unroll
    for (int i = 0; i < 4; i++)
#pragma unroll
        for (int j = 0; j < WNT; j++) acc[i][j] = (f32x4){0.f, 0.f, 0.f, 0.f};

    size_t abase[4], bbase[WNT];
#pragma unroll
    for (int mt = 0; mt < 4; mt++) abase[mt] = ((size_t)((mtb + mt) * KS) * 64 + lane) * 8;
#pragma unroll
    for (int nt = 0; nt < WNT; nt++) bbase[nt] = ((size_t)((ntb + nt) * KS) * 64 + lane) * 8;

#pragma unroll 1
    for (int ks = 0; ks < KS; ks++) {
        const size_t koff = (size_t)ks * 512;   // 64*8 u16 per k-step
        bf16x8 ah[4], al[4], bh[WNT], bl[WNT];
#pragma unroll
        for (int mt = 0; mt < 4; mt++) {
            ah[mt] = *reinterpret_cast<const bf16x8*>(Ah + abase[mt] + koff);
            al[mt] = *reinterpret_cast<const bf16x8*>(Al + abase[mt] + koff);
        }
#pragma unroll
        for (int nt = 0; nt < WNT; nt++) {
            bh[nt] = *reinterpret_cast<const bf16x8*>(Bh + bbase[nt] + koff);
            bl[nt] = *reinterpret_cast<const bf16x8*>(Bl + bbase[nt] + koff);
        }
#pragma unroll
        for (int mt = 0; mt < 4; mt++)
#pragma unroll
            for (int nt = 0; nt < WNT; nt++) {
                acc[mt][nt] = __builtin_amdgcn_mfma_f32_16x16x32_bf16(ah[mt], bh[nt], acc[mt][nt], 0, 0, 0);
                acc[mt][nt] = __builtin_amdgcn_mfma_f32_16x16x32_bf16(ah[mt], bl[nt], acc[mt][nt], 0, 0, 0);
                acc[mt][nt] = __builtin_amdgcn_mfma_f32_16x16x32_bf16(al[mt], bh[nt], acc[mt][nt], 0, 0, 0);
            }
    }

    // C/D layout: n = lane&15, m = (lane>>4)*4 + reg  [m89-verified]
    const int quad = lane >> 4, l15 = lane & 15;
#pragma unroll
    for (int mt = 0; mt < 4; mt++)
#pragma unroll
        for (int nt = 0; nt < WNT; nt++)
#pragma unroll
            for (int reg = 0; reg < 4; reg++) {
                int r = (mtb + mt) * 16 + quad * 4 + reg;
                int c = (ntb + nt) * 16 + l15;
                float v = acc[mt][nt][reg];
                if (GELU) v = 0.5f * v * (1.0f + erff(v * 0.70710678118654752440f));
                C[(size_t)r * N + c] = v;
            }
}

// ================= prep: U = Wi*W_emb (1536x2), cin = Wi*b_emb + bi =================
__global__ void fuse_kernel(const float* __restrict__ Wi_enc, const float* __restrict__ bi_enc,
                            const float* __restrict__ Wi_cell, const float* __restrict__ bi_cell,
                            const float* __restrict__ W_emb, const float* __restrict__ b_emb,
                            float* __restrict__ Ue, float* __restrict__ ce,
                            float* __restrict__ Ud, float* __restrict__ cd) {
    int idx = blockIdx.x * 256 + threadIdx.x;
    if (idx >= 2 * G3) return;
    int which = idx / G3, j = idx % G3;
    const float* Wi = which ? Wi_cell : Wi_enc;
    const float* bi = which ? bi_cell : bi_enc;
    float u0 = 0.f, u1 = 0.f, cc = bi[j];
    for (int k = 0; k < HH; k++) {
        float w = Wi[(size_t)j * HH + k];
        u0 = fmaf(w, W_emb[k * 2 + 0], u0);
        u1 = fmaf(w, W_emb[k * 2 + 1], u1);
        cc = fmaf(w, b_emb[k], cc);
    }
    float* U = which ? Ud : Ue;
    float* cv = which ? cd : ce;
    U[j * 2 + 0] = u0; U[j * 2 + 1] = u1; cv[j] = cc;
}

// ================= prep: pack W_ext into split-bf16 B-fragments =================
// K-ext columns: k<512 -> W[n][k]; k=512,513 -> U[n][0..1] (r,z rows only); k=514 -> const col;
// else 0.  For W1 (U==null): k=514 -> b1[n].
__global__ void pack_frag(const float* __restrict__ W, const float* __restrict__ bh,
                          const float* __restrict__ U, const float* __restrict__ cin,
                          const float* __restrict__ b1,
                          ushortt* __restrict__ Fh, ushortt* __restrict__ Fl, int N) {
    int idx = blockIdx.x * 256 + threadIdx.x;
    if (idx >= N * KS) return;
    int n = idx / KS, ks = idx % KS;
    int nt = n >> 4, l15 = n & 15;
    for (int kl = 0; kl < 32; kl++) {
        int k = ks * 32 + kl;
        float v = 0.f;
        if (k < 512) v = W[(size_t)n * 512 + k];
        else if (k == 512) v = (U && n < 1024) ? U[n * 2 + 0] : 0.f;
        else if (k == 513) v = (U && n < 1024) ? U[n * 2 + 1] : 0.f;
        else if (k == 514) v = U ? ((n < 1024) ? (cin[n] + bh[n]) : bh[n]) : b1[n];
        ushortt hi, lo; splitbf(v, hi, lo);
        int quad = kl >> 3, jj = kl & 7;
        size_t pos = ((size_t)(nt * KS + ks) * 64 + quad * 16 + l15) * 8 + jj;
        Fh[pos] = hi; Fl[pos] = lo;
    }
}

// ================= prep: ctx = z_ctx @ W_ctx^T + b_ctx (32x512) =================
__global__ void ctx_kernel(const float* __restrict__ z, const float* __restrict__ Wc,
                           const float* __restrict__ bc, float* __restrict__ ctx) {
    int idx = blockIdx.x * 256 + threadIdx.x;
    int b = idx >> 9, j = idx & 511;
    float acc = bc[j];
    const float4* zp = (const float4*)(z + (size_t)b * CTXD);
    const float4* wp = (const float4*)(Wc + (size_t)j * CTXD);
    for (int k = 0; k < CTXD / 4; k++) {
        float4 a = zp[k], w = wp[k];
        acc = fmaf(a.x, w.x, fmaf(a.y, w.y, fmaf(a.z, w.z, fmaf(a.w, w.w, acc))));
    }
    ctx[idx] = acc;
}

// ================= init: zero h-frags (ks 0..15), build ks=16 frag (x0,x1,1,0...), state =================
__global__ void init_kernel(const float* __restrict__ traj,
                            ushortt* __restrict__ Ah, ushortt* __restrict__ Al,
                            float* __restrict__ state) {
    if (blockIdx.x < 4096) {
        // zero region: (mt, ks<16) -> 256 u32 each
        int idx = blockIdx.x * 256 + threadIdx.x;       // 0 .. 2^20-1
        int mt = idx >> 12, ks = (idx >> 8) & 15, q = idx & 255;
        size_t pos = ((size_t)(mt * KS + ks) << 8) + q;
        ((unsigned*)Ah)[pos] = 0u;
        ((unsigned*)Al)[pos] = 0u;
    } else {
        // ks=16 frag + state, 16 rows per thread
        for (int rr = 0; rr < 16; rr++) {
            int r = threadIdx.x * 16 + rr;
            int b = r >> 7, o = r & 127;
            float x0 = traj[(size_t)b * (TT * OO * 2) + 0 * OO * 2 + o * 2 + 0];
            float x1 = traj[(size_t)b * (TT * OO * 2) + 0 * OO * 2 + o * 2 + 1];
            ushortt h0, l0, h1, l1;
            splitbf(x0, h0, l0); splitbf(x1, h1, l1);
            int gmt = r >> 4, l15 = r & 15;
            for (int quad = 0; quad < 4; quad++) {
                size_t base = ((size_t)(gmt * KS + 16) * 64 + quad * 16 + l15) * 8;
                for (int jj = 0; jj < 8; jj++) {
                    ushortt vh = 0, vl = 0;
                    if (quad == 0 && jj == 0) { vh = h0; vl = l0; }
                    else if (quad == 0 && jj == 1) { vh = h1; vl = l1; }
                    else if (quad == 0 && jj == 2) { vh = 0x3F80; vl = 0; }  // 1.0
                    Ah[base + jj] = vh; Al[base + jj] = vl;
                }
            }
            state[r * 2 + 0] = traj[(size_t)b * (TT * OO * 2) + 23 * OO * 2 + o * 2 + 0];
            state[r * 2 + 1] = traj[(size_t)b * (TT * OO * 2) + 23 * OO * 2 + o * 2 + 1];
        }
    }
}

// ================= GRU elementwise step =================
// gh holds: [j] full r-preact, [512+j] full z-preact, [1024+j] h-side n-preact (+bh).
// inn (x-side n-preact) computed rank-2 here. h stored ONLY as split-bf16 frags.
template<bool ENC>
__global__ __launch_bounds__(256) void gru_step(const float* __restrict__ gh,
                                                const float* __restrict__ U,
                                                const float* __restrict__ cin,
                                                const float* __restrict__ xsrc, int t,
                                                const float* __restrict__ ctx,
                                                ushortt* __restrict__ Ah,
                                                ushortt* __restrict__ Al) {
    int idx = blockIdx.x * 256 + threadIdx.x;    // 0 .. NN*HH-1
    int r = idx >> 9, j = idx & 511;
    int gmt = r >> 4, l15 = r & 15, ks = j >> 5, kl = j & 31, quad = kl >> 3, jj = kl & 7;
    size_t pos = ((size_t)(gmt * KS + ks) * 64 + quad * 16 + l15) * 8 + jj;
    float hold = bf2f(Ah[pos]) + bf2f(Al[pos]);

    const float* ghp = gh + (size_t)r * G3;
    float pr = ghp[j], pz = ghp[512 + j], hn = ghp[1024 + j];

    float x0, x1;
    if (ENC) {
        const float* p = xsrc + (size_t)(r >> 7) * (TT * OO * 2) + t * OO * 2 + (r & 127) * 2;
        x0 = p[0]; x1 = p[1];
    } else {
        x0 = xsrc[r * 2]; x1 = xsrc[r * 2 + 1];
    }
    float inn = fmaf(x1, U[(1024 + j) * 2 + 1], fmaf(x0, U[(1024 + j) * 2], cin[1024 + j]));
    float rg = 1.f / (1.f + expf(-pr));
    float zg = 1.f / (1.f + expf(-pz));
    float nn = tanhf(inn + rg * hn);
    float h = (1.f - zg) * nn + zg * hold;
    if (ENC && t == TT - 1) h += ctx[(size_t)(r >> 7) * HH + j];

    ushortt hi, lo; splitbf(h, hi, lo);
    Ah[pos] = hi; Al[pos] = lo;

    // encoder: write next step's x into the ks=16 frag (one thread per row)
    if (ENC && j == 0) {
        int tn = (t < TT - 1) ? (t + 1) : (TT - 1);   // t==23 -> state0 = traj[...,23,:]
        const float* p = xsrc + (size_t)(r >> 7) * (TT * OO * 2) + tn * OO * 2 + (r & 127) * 2;
        ushortt h0, l0, h1, l1;
        splitbf(p[0], h0, l0); splitbf(p[1], h1, l1);
        size_t xb = ((size_t)(gmt * KS + 16) * 64 + l15) * 8;   // quad 0
        Ah[xb + 0] = h0; Al[xb + 0] = l0;
        Ah[xb + 1] = h1; Al[xb + 1] = l1;
    }
}

// ================= finalize: d = t1 @ W2^T + b2 ; bounded step ; state ; out ; x-frag =================
__global__ __launch_bounds__(256) void finalize_kernel(const float* __restrict__ t1,
                                                       const float* __restrict__ W2,
                                                       const float* __restrict__ b2,
                                                       float* __restrict__ state,
                                                       float* __restrict__ out, int t,
                                                       ushortt* __restrict__ Ah,
                                                       ushortt* __restrict__ Al) {
    int wave = threadIdx.x >> 6, lane = threadIdx.x & 63;
    int n = blockIdx.x * 4 + wave;               // one wave per row
    const float* row = t1 + (size_t)n * HH;
    float a0 = 0.f, a1 = 0.f;
#pragma unroll
    for (int u = 0; u < 8; u++) {
        float v = row[u * 64 + lane];
        a0 = fmaf(v, W2[u * 64 + lane], a0);
        a1 = fmaf(v, W2[HH + u * 64 + lane], a1);
    }
#pragma unroll
    for (int off = 32; off > 0; off >>= 1) {
        a0 += __shfl_down(a0, off, 64);
        a1 += __shfl_down(a1, off, 64);
    }
    if (lane == 0) {
        float d0 = a0 + b2[0], d1 = a1 + b2[1];
        d0 = 2.0f * tanhf(d0 * 0.5f);
        d1 = 2.0f * tanhf(d1 * 0.5f);
        float s0 = state[n * 2] + d0;
        s0 = fminf(fmaxf(s0, -90.f), 90.f);
        float s1 = state[n * 2 + 1] + d1;
        float rr = fmodf(s1, 360.f);
        if (rr < 0.f) rr += 360.f;   // numpy mod semantics
        state[n * 2] = s0; state[n * 2 + 1] = rr;
        float* op = out + (size_t)((n >> 7) * HOR + t) * (OO * 2) + (n & 127) * 2;
        op[0] = s0; op[1] = rr;
        // next decoder input x = state
        ushortt h0, l0, h1, l1;
        splitbf(s0, h0, l0); splitbf(rr, h1, l1);
        int gmt = n >> 4, l15 = n & 15;
        size_t xb = ((size_t)(gmt * KS + 16) * 64 + l15) * 8;
        Ah[xb + 0] = h0; Al[xb + 0] = l0;
        Ah[xb + 1] = h1; Al[xb + 1] = l1;
    }
}

extern "C" void kernel_launch(void* const* d_in, const int* in_sizes, int n_in,
                              void* d_out, int out_size, void* d_ws, size_t ws_size,
                              hipStream_t stream) {
    const float* z_ctx   = (const float*)d_in[0];
    const float* traj    = (const float*)d_in[1];
    const float* W_emb   = (const float*)d_in[2];
    const float* b_emb   = (const float*)d_in[3];
    const float* W_ctx   = (const float*)d_in[4];
    const float* b_ctx   = (const float*)d_in[5];
    const float* Wi_enc  = (const float*)d_in[6];
    const float* Wh_enc  = (const float*)d_in[7];
    const float* bi_enc  = (const float*)d_in[8];
    const float* bh_enc  = (const float*)d_in[9];
    const float* Wi_cell = (const float*)d_in[10];
    const float* Wh_cell = (const float*)d_in[11];
    const float* bi_cell = (const float*)d_in[12];
    const float* bh_cell = (const float*)d_in[13];
    const float* W1      = (const float*)d_in[14];
    const float* b1      = (const float*)d_in[15];
    const float* W2      = (const float*)d_in[16];
    const float* b2      = (const float*)d_in[17];
    float* out = (float*)d_out;

    // ---- workspace layout (bytes, 256-aligned) ----
    char* ws = (char*)d_ws;
    size_t off = 0;
    auto alloc = [&](size_t bytes) { void* p = ws + off; off += (bytes + 255) & ~(size_t)255; return p; };
    float*   gh    = (float*)  alloc((size_t)NN * G3 * 4);        // 25.2 MB (t1 aliases this)
    ushortt* hAh   = (ushortt*)alloc((size_t)256 * KS * 64 * 8 * 2);  // 4.46 MB
    ushortt* hAl   = (ushortt*)alloc((size_t)256 * KS * 64 * 8 * 2);
    ushortt* WheH  = (ushortt*)alloc((size_t)96 * KS * 64 * 8 * 2);   // 1.67 MB
    ushortt* WheL  = (ushortt*)alloc((size_t)96 * KS * 64 * 8 * 2);
    ushortt* WhdH  = (ushortt*)alloc((size_t)96 * KS * 64 * 8 * 2);
    ushortt* WhdL  = (ushortt*)alloc((size_t)96 * KS * 64 * 8 * 2);
    ushortt* W1H   = (ushortt*)alloc((size_t)32 * KS * 64 * 8 * 2);   // 0.56 MB
    ushortt* W1L   = (ushortt*)alloc((size_t)32 * KS * 64 * 8 * 2);
    float*   state = (float*)  alloc((size_t)NN * 2 * 4);
    float*   ctxb  = (float*)  alloc((size_t)BB * HH * 4);
    float*   Ue    = (float*)  alloc((size_t)G3 * 2 * 4);
    float*   ce    = (float*)  alloc((size_t)G3 * 4);
    float*   Ud    = (float*)  alloc((size_t)G3 * 2 * 4);
    float*   cd    = (float*)  alloc((size_t)G3 * 4);
    float*   t1    = gh;   // alias: gh is dead once gru_step consumed it

    // ---- prep (runs every call; ws is re-poisoned) ----
    fuse_kernel<<<(2 * G3 + 255) / 256, 256, 0, stream>>>(Wi_enc, bi_enc, Wi_cell, bi_cell,
                                                          W_emb, b_emb, Ue, ce, Ud, cd);
    ctx_kernel<<<(BB * HH) / 256, 256, 0, stream>>>(z_ctx, W_ctx, b_ctx, ctxb);
    pack_frag<<<(G3 * KS + 255) / 256, 256, 0, stream>>>(Wh_enc, bh_enc, Ue, ce, nullptr, WheH, WheL, G3);
    pack_frag<<<(G3 * KS + 255) / 256, 256, 0, stream>>>(Wh_cell, bh_cell, Ud, cd, nullptr, WhdH, WhdL, G3);
    pack_frag<<<(HH * KS + 255) / 256, 256, 0, stream>>>(W1, nullptr, nullptr, nullptr, b1, W1H, W1L, HH);
    init_kernel<<<4097, 256, 0, stream>>>(traj, hAh, hAl, state);

    const int gemm3_grid = (NN / 128) * (G3 / 96);   // 32*16 = 512
    const int gemmW_grid = (NN / 128) * (HH / 64);   // 32*8  = 256
    const int ew_blocks = (NN * HH) / 256;           // 8192

    // ---- encoder: 24 GRU steps ----
    for (int t = 0; t < TT; t++) {
        gemm_frag<3, false><<<gemm3_grid, 256, 0, stream>>>(hAh, hAl, WheH, WheL, gh, G3);
        gru_step<true><<<ew_blocks, 256, 0, stream>>>(gh, Ue, ce, traj, t, ctxb, hAh, hAl);
    }

    // ---- decoder: 48 steps ----
    for (int t = 0; t < HOR; t++) {
        gemm_frag<3, false><<<gemm3_grid, 256, 0, stream>>>(hAh, hAl, WhdH, WhdL, gh, G3);
        gru_step<false><<<ew_blocks, 256, 0, stream>>>(gh, Ud, cd, state, t, nullptr, hAh, hAl);
        gemm_frag<2, true><<<gemmW_grid, 256, 0, stream>>>(hAh, hAl, W1H, W1L, t1, HH);
        finalize_kernel<<<NN / 4, 256, 0, stream>>>(t1, W2, b2, state, out, t, hAh, hAl);
    }
}

// Round 3
// 3796.793 us; speedup vs baseline: 2.5460x; 1.5253x over previous
//
#include <hip/hip_runtime.h>
#include <hip/hip_bf16.h>
#include <math.h>

// Problem constants (MiniTrajectoryPredictor)
#define BB 32
#define TT 24
#define OO 128
#define HH 512
#define CTXD 256
#define HOR 48
#define NN (BB*OO)        // 4096
#define G3 (3*HH)         // 1536
#define KS 17             // k-steps of 32 (512 h + [x0,x1,1] + pad)

typedef unsigned short ushortt;
typedef __attribute__((ext_vector_type(8))) short bf16x8;
typedef __attribute__((ext_vector_type(4))) float f32x4;

// ---- bf16 split helpers ----
__device__ __forceinline__ ushortt f2bf(float x) {
    union { float f; unsigned u; } v; v.f = x;
    unsigned r = v.u + 0x7FFF + ((v.u >> 16) & 1);
    return (ushortt)(r >> 16);
}
__device__ __forceinline__ float bf2f(ushortt b) {
    union { unsigned u; float f; } v; v.u = ((unsigned)b) << 16;
    return v.f;
}
__device__ __forceinline__ void splitbf(float x, ushortt& hi, ushortt& lo) {
    hi = f2bf(x);
    lo = f2bf(x - bf2f(hi));
}
__device__ __forceinline__ float sigm(float x) { return 1.f / (1.f + __expf(-x)); }
__device__ __forceinline__ float tanh_fast(float x) {
    float xc = fminf(fmaxf(x, -10.f), 10.f);
    float e = __expf(2.f * xc);
    return (e - 1.f) / (e + 1.f);
}

// Fragment layout (verified in round 2): element (row r, k) of a 16-row tile lives at
// lane = ((k%32)>>3)*16 + (r%16), slot = k%8; buffer [tile][ks][lane][slot] u16.
// C/D: col = lane&15, row = (lane>>4)*4 + reg.

// ================= fused gh-GEMM + GRU step =================
// C = h_ext(4096 x 544) @ Wh_ext(1536 x 544)^T, 3-pass split-bf16.
// Block: BM=128 (8 m-tiles), BJ=32 cols per gate (2 j-tiles -> 6 n-tiles: gates {j,512+j,1024+j}).
// Wave w: 2 m-tiles (disjoint), all 6 n-tiles. Grid 32 x 16 = 512.
// Epilogue does the full GRU update and writes h_new A-frags (double-buffered).

#define STEP_LOADA(Adst, ksv) do { \
  const size_t koff = (size_t)(ksv) * 512; \
  _Pragma("unroll") for (int mt_ = 0; mt_ < 2; mt_++) { \
    Adst[mt_*2+0] = *reinterpret_cast<const bf16x8*>(RAh + ao[mt_] + koff); \
    Adst[mt_*2+1] = *reinterpret_cast<const bf16x8*>(RAl + ao[mt_] + koff); \
  } } while(0)
#define STEP_LOADB(Bdst, ksv) do { \
  const size_t koff = (size_t)(ksv) * 512; \
  _Pragma("unroll") for (int i_ = 0; i_ < 6; i_++) { \
    Bdst[i_*2+0] = *reinterpret_cast<const bf16x8*>(Bh + bo[i_] + koff); \
    Bdst[i_*2+1] = *reinterpret_cast<const bf16x8*>(Bl + bo[i_] + koff); \
  } } while(0)
#define STEP_MFMA(Av, Bv) do { \
  _Pragma("unroll") for (int mt_ = 0; mt_ < 2; mt_++) \
  _Pragma("unroll") for (int i_ = 0; i_ < 6; i_++) \
    acc[mt_][i_] = __builtin_amdgcn_mfma_f32_16x16x32_bf16(Av[mt_*2+0], Bv[i_*2+0], acc[mt_][i_], 0,0,0); \
  _Pragma("unroll") for (int mt_ = 0; mt_ < 2; mt_++) \
  _Pragma("unroll") for (int i_ = 0; i_ < 6; i_++) \
    acc[mt_][i_] = __builtin_amdgcn_mfma_f32_16x16x32_bf16(Av[mt_*2+0], Bv[i_*2+1], acc[mt_][i_], 0,0,0); \
  _Pragma("unroll") for (int mt_ = 0; mt_ < 2; mt_++) \
  _Pragma("unroll") for (int i_ = 0; i_ < 6; i_++) \
    acc[mt_][i_] = __builtin_amdgcn_mfma_f32_16x16x32_bf16(Av[mt_*2+1], Bv[i_*2+0], acc[mt_][i_], 0,0,0); \
  } while(0)

template<bool ENC>
__global__ __launch_bounds__(256, 2) void step_kernel(
    const ushortt* __restrict__ RAh, const ushortt* __restrict__ RAl,   // read h frags
    ushortt* __restrict__ WAh, ushortt* __restrict__ WAl,               // write h frags
    const ushortt* __restrict__ Bh, const ushortt* __restrict__ Bl,     // Wh_ext frags
    const float* __restrict__ U, const float* __restrict__ cin,
    const float* __restrict__ xsrc, int t, const float* __restrict__ ctx)
{
    __shared__ float hbuf[128 * 36];   // stride 36 (16B-aligned rows, conflict-light)
    const int mb = blockIdx.x >> 4;    // 0..31
    const int jb = blockIdx.x & 15;    // 0..15 (32 cols per gate)
    const int w = threadIdx.x >> 6, lane = threadIdx.x & 63;
    const int quad = lane >> 4, l15 = lane & 15;
    const int mtg = mb * 8 + w * 2;    // wave's 2 global m-tiles

    f32x4 acc[2][6];
#pragma unroll
    for (int a = 0; a < 2; a++)
#pragma unroll
        for (int b = 0; b < 6; b++) acc[a][b] = (f32x4){0.f,0.f,0.f,0.f};

    size_t ao[2];
    unsigned bo[6];
#pragma unroll
    for (int mt = 0; mt < 2; mt++) ao[mt] = (size_t)(mtg + mt) * (KS*512) + lane * 8;
#pragma unroll
    for (int g = 0; g < 3; g++)
#pragma unroll
        for (int jt = 0; jt < 2; jt++)
            bo[g*2+jt] = (unsigned)(g*32 + jb*2 + jt) * (KS*512) + lane * 8;

    bf16x8 aC[4], bC[12], aN[4], bN[12];
    STEP_LOADA(aC, 0); STEP_LOADB(bC, 0);
#pragma unroll 1
    for (int ks = 0; ks < 16; ks += 2) {
        STEP_LOADA(aN, ks+1); STEP_LOADB(bN, ks+1);
        STEP_MFMA(aC, bC);
        STEP_LOADA(aC, ks+2); STEP_LOADB(bC, ks+2);
        STEP_MFMA(aN, bN);
    }
    STEP_MFMA(aC, bC);

    // ---------------- GRU epilogue ----------------
    const int jlo = jb * 32;
    float u0[2], u1[2], cc[2];
#pragma unroll
    for (int jt = 0; jt < 2; jt++) {
        int j = jlo + jt*16 + l15;
        u0[jt] = U[(1024 + j) * 2];
        u1[jt] = U[(1024 + j) * 2 + 1];
        cc[jt] = cin[1024 + j];
    }
    float x0v[2][4], x1v[2][4];
#pragma unroll
    for (int mt = 0; mt < 2; mt++)
#pragma unroll
        for (int reg = 0; reg < 4; reg++) {
            int row = (mtg + mt) * 16 + quad * 4 + reg;
            const float* p;
            if (ENC) p = xsrc + (((size_t)(row >> 7) * TT + t) * OO + (row & 127)) * 2;
            else     p = xsrc + (size_t)row * 2;
            x0v[mt][reg] = p[0]; x1v[mt][reg] = p[1];
        }
#pragma unroll
    for (int mt = 0; mt < 2; mt++)
#pragma unroll
        for (int jt = 0; jt < 2; jt++) {
            int qk = jt*2 + (l15 >> 3), slot = l15 & 7;
#pragma unroll
            for (int reg = 0; reg < 4; reg++) {
                int row = (mtg + mt) * 16 + quad * 4 + reg;
                float pr = acc[mt][0*2+jt][reg];
                float pz = acc[mt][1*2+jt][reg];
                float hn = acc[mt][2*2+jt][reg];
                size_t pos = (((size_t)(mtg + mt) * KS + jb) * 64 + qk*16 + quad*4 + reg) * 8 + slot;
                float hold = bf2f(RAh[pos]) + bf2f(RAl[pos]);
                float inn = fmaf(x1v[mt][reg], u1[jt], fmaf(x0v[mt][reg], u0[jt], cc[jt]));
                float rg = sigm(pr), zg = sigm(pz);
                float nn = tanh_fast(inn + rg * hn);
                float h = (1.f - zg) * nn + zg * hold;
                if (ENC && t == TT - 1) h += ctx[(size_t)(row >> 7) * HH + jlo + jt*16 + l15];
                hbuf[(w*32 + mt*16 + quad*4 + reg) * 36 + jt*16 + l15] = h;
            }
        }
    __syncthreads();
    // repack LDS tile -> A-frags of write buffer (block covers frag ks == jb)
#pragma unroll
    for (int rr = 0; rr < 2; rr++) {
        int fr = threadIdx.x + 256 * rr;       // 0..511
        int mt8 = fr >> 6, fl = fr & 63;
        int qk = fl >> 4, rloc = mt8 * 16 + (fl & 15);
        const float* src = &hbuf[rloc * 36 + qk * 8];
        bf16x8 hv, lv;
#pragma unroll
        for (int s = 0; s < 8; s++) {
            ushortt hi, lo; splitbf(src[s], hi, lo);
            hv[s] = (short)hi; lv[s] = (short)lo;
        }
        size_t base = (((size_t)(mb*8 + mt8) * KS + jb) * 64 + fl) * 8;
        *reinterpret_cast<bf16x8*>(WAh + base) = hv;
        *reinterpret_cast<bf16x8*>(WAl + base) = lv;
    }
    // encoder write-ahead: next step's x into write buffer ks=16 (slots 0,1)
    if (ENC && jb == 0 && threadIdx.x < 128) {
        int row = mb * 128 + threadIdx.x;
        int tn = (t < TT - 1) ? (t + 1) : (TT - 1);
        const float* p = xsrc + (((size_t)(row >> 7) * TT + tn) * OO + (row & 127)) * 2;
        ushortt h0, l0, h1, l1;
        splitbf(p[0], h0, l0); splitbf(p[1], h1, l1);
        size_t xb = (((size_t)(row >> 4) * KS + 16) * 64 + (row & 15)) * 8;
        WAh[xb + 0] = h0; WAl[xb + 0] = l0;
        WAh[xb + 1] = h1; WAl[xb + 1] = l1;
    }
}

// ================= fused head: t1 = gelu(h@W1^T + b1); d += t1@W2^T; last block finalizes =================
// BM=64, BN=64, grid 64 x 8 = 512 blocks. Wave: 2 mt x 2 nt.
#define HEAD_LOADA(Adst, ksv) do { \
  const size_t koff = (size_t)(ksv) * 512; \
  _Pragma("unroll") for (int mt_ = 0; mt_ < 2; mt_++) { \
    Adst[mt_*2+0] = *reinterpret_cast<const bf16x8*>(Ah + hao[mt_] + koff); \
    Adst[mt_*2+1] = *reinterpret_cast<const bf16x8*>(Al + hao[mt_] + koff); \
  } } while(0)
#define HEAD_LOADB(Bdst, ksv) do { \
  const size_t koff = (size_t)(ksv) * 512; \
  _Pragma("unroll") for (int nt_ = 0; nt_ < 2; nt_++) { \
    Bdst[nt_*2+0] = *reinterpret_cast<const bf16x8*>(Bh + hbo[nt_] + koff); \
    Bdst[nt_*2+1] = *reinterpret_cast<const bf16x8*>(Bl + hbo[nt_] + koff); \
  } } while(0)
#define HEAD_MFMA(Av, Bv) do { \
  _Pragma("unroll") for (int mt_ = 0; mt_ < 2; mt_++) \
  _Pragma("unroll") for (int nt_ = 0; nt_ < 2; nt_++) { \
    acc[mt_][nt_] = __builtin_amdgcn_mfma_f32_16x16x32_bf16(Av[mt_*2+0], Bv[nt_*2+0], acc[mt_][nt_], 0,0,0); \
    acc[mt_][nt_] = __builtin_amdgcn_mfma_f32_16x16x32_bf16(Av[mt_*2+0], Bv[nt_*2+1], acc[mt_][nt_], 0,0,0); \
    acc[mt_][nt_] = __builtin_amdgcn_mfma_f32_16x16x32_bf16(Av[mt_*2+1], Bv[nt_*2+0], acc[mt_][nt_], 0,0,0); \
  } } while(0)

__global__ __launch_bounds__(256) void head_kernel(
    ushortt* Ah, ushortt* Al,                 // h frags (also x write target) -- no restrict (aliased use)
    const ushortt* __restrict__ Bh, const ushortt* __restrict__ Bl,   // W1_ext frags
    const float* __restrict__ W2, const float* __restrict__ b2,
    float* __restrict__ d, unsigned* __restrict__ ctr,
    float* state, float* __restrict__ out, int t)
{
    const int mb = blockIdx.x >> 3;   // 0..63
    const int nb = blockIdx.x & 7;    // 0..7
    const int w = threadIdx.x >> 6, lane = threadIdx.x & 63;
    const int quad = lane >> 4, l15 = lane & 15;
    const int mtb = mb * 4 + (w & 1) * 2;
    const int ntb = nb * 4 + (w >> 1) * 2;

    f32x4 acc[2][2];
#pragma unroll
    for (int a = 0; a < 2; a++)
#pragma unroll
        for (int b = 0; b < 2; b++) acc[a][b] = (f32x4){0.f,0.f,0.f,0.f};

    size_t hao[2]; unsigned hbo[2];
#pragma unroll
    for (int mt = 0; mt < 2; mt++) hao[mt] = (size_t)(mtb + mt) * (KS*512) + lane * 8;
#pragma unroll
    for (int nt = 0; nt < 2; nt++) hbo[nt] = (unsigned)(ntb + nt) * (KS*512) + lane * 8;

    bf16x8 aC[4], bC[4], aN[4], bN[4];
    HEAD_LOADA(aC, 0); HEAD_LOADB(bC, 0);
#pragma unroll 1
    for (int ks = 0; ks < 16; ks += 2) {
        HEAD_LOADA(aN, ks+1); HEAD_LOADB(bN, ks+1);
        HEAD_MFMA(aC, bC);
        HEAD_LOADA(aC, ks+2); HEAD_LOADB(bC, ks+2);
        HEAD_MFMA(aN, bN);
    }
    HEAD_MFMA(aC, bC);

    // ---- GELU + W2 partial reduction ----
    float w2a[2], w2b[2];
#pragma unroll
    for (int nt = 0; nt < 2; nt++) {
        int col = (ntb + nt) * 16 + l15;
        w2a[nt] = W2[col]; w2b[nt] = W2[HH + col];
    }
    float p0[2][4], p1[2][4];
#pragma unroll
    for (int mt = 0; mt < 2; mt++)
#pragma unroll
        for (int reg = 0; reg < 4; reg++) { p0[mt][reg] = 0.f; p1[mt][reg] = 0.f; }
#pragma unroll
    for (int mt = 0; mt < 2; mt++)
#pragma unroll
        for (int nt = 0; nt < 2; nt++)
#pragma unroll
            for (int reg = 0; reg < 4; reg++) {
                float v = acc[mt][nt][reg];
                v = 0.5f * v * (1.0f + erff(v * 0.70710678118654752440f));
                p0[mt][reg] = fmaf(v, w2a[nt], p0[mt][reg]);
                p1[mt][reg] = fmaf(v, w2b[nt], p1[mt][reg]);
            }
#pragma unroll
    for (int m = 1; m < 16; m <<= 1)
#pragma unroll
        for (int mt = 0; mt < 2; mt++)
#pragma unroll
            for (int reg = 0; reg < 4; reg++) {
                p0[mt][reg] += __shfl_xor(p0[mt][reg], m, 64);
                p1[mt][reg] += __shfl_xor(p1[mt][reg], m, 64);
            }
    if (l15 == 0) {
#pragma unroll
        for (int mt = 0; mt < 2; mt++)
#pragma unroll
            for (int reg = 0; reg < 4; reg++) {
                int row = (mtb + mt) * 16 + quad * 4 + reg;
                atomicAdd(&d[row * 2], p0[mt][reg]);
                atomicAdd(&d[row * 2 + 1], p1[mt][reg]);
            }
    }

    // ---- last-block finalize ----
    __syncthreads();                    // drains this block's atomics (waitcnt before barrier)
    __shared__ unsigned lastv;
    if (threadIdx.x == 0) lastv = atomicAdd(ctr, 1u);
    __syncthreads();
    if (lastv == 511) {
        __threadfence();
#pragma unroll 1
        for (int rr = 0; rr < 16; rr++) {
            int row = rr * 256 + threadIdx.x;
            float d0 = d[row * 2]     + b2[0];
            float d1 = d[row * 2 + 1] + b2[1];
            d0 = 2.0f * tanhf(d0 * 0.5f);
            d1 = 2.0f * tanhf(d1 * 0.5f);
            float s0 = state[row * 2] + d0;
            s0 = fminf(fmaxf(s0, -90.f), 90.f);
            float s1 = state[row * 2 + 1] + d1;
            float rrm = fmodf(s1, 360.f);
            if (rrm < 0.f) rrm += 360.f;
            state[row * 2] = s0; state[row * 2 + 1] = rrm;
            float* op = out + (((size_t)(row >> 7) * HOR + t) * OO + (row & 127)) * 2;
            op[0] = s0; op[1] = rrm;
            ushortt h0, l0, h1, l1;
            splitbf(s0, h0, l0); splitbf(rrm, h1, l1);
            size_t xb = (((size_t)(row >> 4) * KS + 16) * 64 + (row & 15)) * 8;
            Ah[xb + 0] = h0; Al[xb + 0] = l0;
            Ah[xb + 1] = h1; Al[xb + 1] = l1;
        }
    }
}

// ================= prep: U = Wi*W_emb, cin = Wi*b_emb + bi =================
__global__ void fuse_kernel(const float* __restrict__ Wi_enc, const float* __restrict__ bi_enc,
                            const float* __restrict__ Wi_cell, const float* __restrict__ bi_cell,
                            const float* __restrict__ W_emb, const float* __restrict__ b_emb,
                            float* __restrict__ Ue, float* __restrict__ ce,
                            float* __restrict__ Ud, float* __restrict__ cd) {
    int idx = blockIdx.x * 256 + threadIdx.x;
    if (idx >= 2 * G3) return;
    int which = idx / G3, j = idx % G3;
    const float* Wi = which ? Wi_cell : Wi_enc;
    const float* bi = which ? bi_cell : bi_enc;
    float u0 = 0.f, u1 = 0.f, cc = bi[j];
    for (int k = 0; k < HH; k++) {
        float w = Wi[(size_t)j * HH + k];
        u0 = fmaf(w, W_emb[k * 2 + 0], u0);
        u1 = fmaf(w, W_emb[k * 2 + 1], u1);
        cc = fmaf(w, b_emb[k], cc);
    }
    float* Uo = which ? Ud : Ue;
    float* cv = which ? cd : ce;
    Uo[j * 2 + 0] = u0; Uo[j * 2 + 1] = u1; cv[j] = cc;
}

// ================= prep: pack W_ext into split-bf16 B-frags =================
__global__ void pack_frag(const float* __restrict__ W, const float* __restrict__ bhv,
                          const float* __restrict__ U, const float* __restrict__ cin,
                          const float* __restrict__ b1,
                          ushortt* __restrict__ Fh, ushortt* __restrict__ Fl, int N) {
    int idx = blockIdx.x * 256 + threadIdx.x;
    if (idx >= N * KS) return;
    int n = idx / KS, ks = idx % KS;
    int nt = n >> 4, l15 = n & 15;
    for (int kl = 0; kl < 32; kl++) {
        int k = ks * 32 + kl;
        float v = 0.f;
        if (k < 512) v = W[(size_t)n * 512 + k];
        else if (k == 512) v = (U && n < 1024) ? U[n * 2 + 0] : 0.f;
        else if (k == 513) v = (U && n < 1024) ? U[n * 2 + 1] : 0.f;
        else if (k == 514) v = U ? ((n < 1024) ? (cin[n] + bhv[n]) : bhv[n]) : b1[n];
        ushortt hi, lo; splitbf(v, hi, lo);
        int quad = kl >> 3, jj = kl & 7;
        size_t pos = ((size_t)(nt * KS + ks) * 64 + quad * 16 + l15) * 8 + jj;
        Fh[pos] = hi; Fl[pos] = lo;
    }
}

// ================= prep: ctx = z_ctx @ W_ctx^T + b_ctx =================
__global__ void ctx_kernel(const float* __restrict__ z, const float* __restrict__ Wc,
                           const float* __restrict__ bc, float* __restrict__ ctx) {
    int idx = blockIdx.x * 256 + threadIdx.x;
    int b = idx >> 9, j = idx & 511;
    float acc = bc[j];
    const float4* zp = (const float4*)(z + (size_t)b * CTXD);
    const float4* wp = (const float4*)(Wc + (size_t)j * CTXD);
    for (int k = 0; k < CTXD / 4; k++) {
        float4 a = zp[k], ww = wp[k];
        acc = fmaf(a.x, ww.x, fmaf(a.y, ww.y, fmaf(a.z, ww.z, fmaf(a.w, ww.w, acc))));
    }
    ctx[idx] = acc;
}

// ================= init =================
__global__ void init_kernel(const float* __restrict__ traj,
                            ushortt* __restrict__ Ah0, ushortt* __restrict__ Al0,
                            ushortt* __restrict__ Ah1, ushortt* __restrict__ Al1,
                            float* __restrict__ state, float* __restrict__ d,
                            unsigned* __restrict__ ctr) {
    int b = blockIdx.x;
    if (b < 1024) {
        // zero buf0 frag ks 0..15 (h = 0)
        int item = b * 256 + threadIdx.x;         // 0..262143
        int mt = item >> 10, ks = (item >> 6) & 15, q4 = item & 63;
        size_t pos32 = ((size_t)(mt * KS + ks)) * 256 + q4 * 4;
        uint4 z = {0u,0u,0u,0u};
        *reinterpret_cast<uint4*>(((unsigned*)Ah0) + pos32) = z;
        *reinterpret_cast<uint4*>(((unsigned*)Al0) + pos32) = z;
    } else if (b < 1040) {
        // ks=16 of both bufs + x0 (buf0) + state
        int row = (b - 1024) * 256 + threadIdx.x;  // 0..4095
        int bi = row >> 7, o = row & 127;
        const float* tp = traj + (((size_t)bi * TT + 0) * OO + o) * 2;
        ushortt xh0, xl0, xh1, xl1;
        splitbf(tp[0], xh0, xl0); splitbf(tp[1], xh1, xl1);
        for (int qk = 0; qk < 4; qk++)
            for (int slot = 0; slot < 8; slot++) {
                size_t p = (((size_t)(row >> 4) * KS + 16) * 64 + qk * 16 + (row & 15)) * 8 + slot;
                ushortt vh0 = 0, vl0 = 0, vh1 = 0;
                if (qk == 0 && slot == 0) { vh0 = xh0; vl0 = xl0; }
                else if (qk == 0 && slot == 1) { vh0 = xh1; vl0 = xl1; }
                else if (qk == 0 && slot == 2) { vh0 = 0x3F80; vh1 = 0x3F80; }
                Ah0[p] = vh0; Al0[p] = vl0; Ah1[p] = vh1; Al1[p] = 0;
            }
        const float* sp = traj + (((size_t)bi * TT + 23) * OO + o) * 2;
        state[row * 2] = sp[0]; state[row * 2 + 1] = sp[1];
    } else if (b < 1424) {
        // zero d buffers (48 * 4096 * 2 floats = 98304 float4)
        int i = (b - 1040) * 256 + threadIdx.x;
        float4 z = {0.f,0.f,0.f,0.f};
        reinterpret_cast<float4*>(d)[i] = z;
    } else {
        if (threadIdx.x < 48) ctr[threadIdx.x] = 0u;
    }
}

extern "C" void kernel_launch(void* const* d_in, const int* in_sizes, int n_in,
                              void* d_out, int out_size, void* d_ws, size_t ws_size,
                              hipStream_t stream) {
    const float* z_ctx   = (const float*)d_in[0];
    const float* traj    = (const float*)d_in[1];
    const float* W_emb   = (const float*)d_in[2];
    const float* b_emb   = (const float*)d_in[3];
    const float* W_ctx   = (const float*)d_in[4];
    const float* b_ctx   = (const float*)d_in[5];
    const float* Wi_enc  = (const float*)d_in[6];
    const float* Wh_enc  = (const float*)d_in[7];
    const float* bi_enc  = (const float*)d_in[8];
    const float* bh_enc  = (const float*)d_in[9];
    const float* Wi_cell = (const float*)d_in[10];
    const float* Wh_cell = (const float*)d_in[11];
    const float* bi_cell = (const float*)d_in[12];
    const float* bh_cell = (const float*)d_in[13];
    const float* W1      = (const float*)d_in[14];
    const float* b1      = (const float*)d_in[15];
    const float* W2      = (const float*)d_in[16];
    const float* b2      = (const float*)d_in[17];
    float* out = (float*)d_out;

    char* ws = (char*)d_ws;
    size_t off = 0;
    auto alloc = [&](size_t bytes) { void* p = ws + off; off += (bytes + 255) & ~(size_t)255; return p; };
    const size_t hfrag = (size_t)256 * KS * 512 * 2;   // bytes per h frag buf
    const size_t wfrag = (size_t)96  * KS * 512 * 2;
    const size_t w1frag = (size_t)32 * KS * 512 * 2;
    ushortt* Ah0 = (ushortt*)alloc(hfrag);
    ushortt* Al0 = (ushortt*)alloc(hfrag);
    ushortt* Ah1 = (ushortt*)alloc(hfrag);
    ushortt* Al1 = (ushortt*)alloc(hfrag);
    ushortt* WheH = (ushortt*)alloc(wfrag);
    ushortt* WheL = (ushortt*)alloc(wfrag);
    ushortt* WhdH = (ushortt*)alloc(wfrag);
    ushortt* WhdL = (ushortt*)alloc(wfrag);
    ushortt* W1H  = (ushortt*)alloc(w1frag);
    ushortt* W1L  = (ushortt*)alloc(w1frag);
    float*   state = (float*)alloc((size_t)NN * 2 * 4);
    float*   ctxb  = (float*)alloc((size_t)BB * HH * 4);
    float*   Ue    = (float*)alloc((size_t)G3 * 2 * 4);
    float*   ce    = (float*)alloc((size_t)G3 * 4);
    float*   Ud    = (float*)alloc((size_t)G3 * 2 * 4);
    float*   cd    = (float*)alloc((size_t)G3 * 4);
    float*   dbuf  = (float*)alloc((size_t)HOR * NN * 2 * 4);
    unsigned* ctr  = (unsigned*)alloc(HOR * 4);

    ushortt* bufAh[2] = {Ah0, Ah1};
    ushortt* bufAl[2] = {Al0, Al1};

    fuse_kernel<<<(2 * G3 + 255) / 256, 256, 0, stream>>>(Wi_enc, bi_enc, Wi_cell, bi_cell,
                                                          W_emb, b_emb, Ue, ce, Ud, cd);
    ctx_kernel<<<(BB * HH) / 256, 256, 0, stream>>>(z_ctx, W_ctx, b_ctx, ctxb);
    pack_frag<<<(G3 * KS + 255) / 256, 256, 0, stream>>>(Wh_enc, bh_enc, Ue, ce, nullptr, WheH, WheL, G3);
    pack_frag<<<(G3 * KS + 255) / 256, 256, 0, stream>>>(Wh_cell, bh_cell, Ud, cd, nullptr, WhdH, WhdL, G3);
    pack_frag<<<(HH * KS + 255) / 256, 256, 0, stream>>>(W1, nullptr, nullptr, nullptr, b1, W1H, W1L, HH);
    init_kernel<<<1425, 256, 0, stream>>>(traj, Ah0, Al0, Ah1, Al1, state, dbuf, ctr);

    // ---- encoder: 24 fused steps ----
    for (int t = 0; t < TT; t++) {
        int rp = t & 1, wp = (t + 1) & 1;
        step_kernel<true><<<512, 256, 0, stream>>>(bufAh[rp], bufAl[rp], bufAh[wp], bufAl[wp],
                                                   WheH, WheL, Ue, ce, traj, t, ctxb);
    }
    // ---- decoder: 48 steps x (step + head) ----
    for (int t = 0; t < HOR; t++) {
        int s = TT + t;
        int rp = s & 1, wp = (s + 1) & 1;
        step_kernel<false><<<512, 256, 0, stream>>>(bufAh[rp], bufAl[rp], bufAh[wp], bufAl[wp],
                                                    WhdH, WhdL, Ud, cd, state, t, nullptr);
        head_kernel<<<512, 256, 0, stream>>>(bufAh[wp], bufAl[wp], W1H, W1L, W2, b2,
                                             dbuf + (size_t)t * NN * 2, ctr + t, state, out, t);
    }
}